// Round 1
// baseline (216.219 us; speedup 1.0000x reference)
//
#include <hip/hip_runtime.h>
#include <math.h>

static constexpr int kL  = 4096;   // H*W
static constexpr int kDI = 256;

__device__ __forceinline__ float sigmoidf_(float x) { return 1.0f / (1.0f + __expf(-x)); }
__device__ __forceinline__ float siluf_(float x)    { return x * sigmoidf_(x); }
__device__ __forceinline__ float softplusf_(float x){ return (x > 20.0f) ? x : log1pf(__expf(x)); }

// ---------------------------------------------------------------------------
// Generic tiled f32 GEMM: C[(b*CS + m0+m)*kL + l] = sum_k A[m*K+k] * X[(b*XS+k)*kL + l]
// grid.x = 128 (b in high bit, 64 l-tiles of 64), grid.y = M/64
// ---------------------------------------------------------------------------
__global__ __launch_bounds__(256) void k_gemm(const float* __restrict__ A,
                                              const float* __restrict__ X,
                                              float* __restrict__ C,
                                              int K, int XS, int CS)
{
    __shared__ float As[16][68];
    __shared__ float Bs[16][64];
    const int t  = threadIdx.x;
    const int nt = blockIdx.x;
    const int b  = nt >> 6;
    const int l0 = (nt & 63) << 6;
    const int m0 = blockIdx.y * 64;
    const int tx = t & 15, ty = t >> 4;

    const float* Ab = A + (size_t)m0 * K;
    const float* Xb = X + (size_t)(b * XS) * kL + l0;

    const int am = t >> 2, ak = (t & 3) * 4;   // A-tile element (m, k..k+3)
    const int bk = t >> 4, bn = (t & 15) * 4;  // X-tile element (k, n..n+3)

    float acc[4][4] = {};
    for (int k0 = 0; k0 < K; k0 += 16) {
        float4 a4 = *(const float4*)(Ab + (size_t)am * K + k0 + ak);
        As[ak + 0][am] = a4.x; As[ak + 1][am] = a4.y;
        As[ak + 2][am] = a4.z; As[ak + 3][am] = a4.w;
        float4 b4 = *(const float4*)(Xb + (size_t)(k0 + bk) * kL + bn);
        *(float4*)&Bs[bk][bn] = b4;
        __syncthreads();
#pragma unroll
        for (int k = 0; k < 16; ++k) {
            float4 av = *(const float4*)&As[k][ty * 4];
            float4 bv = *(const float4*)&Bs[k][tx * 4];
            acc[0][0] = fmaf(av.x, bv.x, acc[0][0]);
            acc[0][1] = fmaf(av.x, bv.y, acc[0][1]);
            acc[0][2] = fmaf(av.x, bv.z, acc[0][2]);
            acc[0][3] = fmaf(av.x, bv.w, acc[0][3]);
            acc[1][0] = fmaf(av.y, bv.x, acc[1][0]);
            acc[1][1] = fmaf(av.y, bv.y, acc[1][1]);
            acc[1][2] = fmaf(av.y, bv.z, acc[1][2]);
            acc[1][3] = fmaf(av.y, bv.w, acc[1][3]);
            acc[2][0] = fmaf(av.z, bv.x, acc[2][0]);
            acc[2][1] = fmaf(av.z, bv.y, acc[2][1]);
            acc[2][2] = fmaf(av.z, bv.z, acc[2][2]);
            acc[2][3] = fmaf(av.z, bv.w, acc[2][3]);
            acc[3][0] = fmaf(av.w, bv.x, acc[3][0]);
            acc[3][1] = fmaf(av.w, bv.y, acc[3][1]);
            acc[3][2] = fmaf(av.w, bv.z, acc[3][2]);
            acc[3][3] = fmaf(av.w, bv.w, acc[3][3]);
        }
        __syncthreads();
    }
    float* Cb = C + (size_t)(b * CS + m0) * kL + l0;
#pragma unroll
    for (int i = 0; i < 4; ++i) {
        float4 v = make_float4(acc[i][0], acc[i][1], acc[i][2], acc[i][3]);
        *(float4*)&Cb[(size_t)(ty * 4 + i) * kL + tx * 4] = v;
    }
}

// ---------------------------------------------------------------------------
// Depthwise 5x5 conv (pad 2), in place on xz, one block per (b,c) plane.
// For c < 256 (x half) also emits mean/max over L (for channel attention).
// ---------------------------------------------------------------------------
__global__ __launch_bounds__(256) void k_dwconv(float* __restrict__ xz,
                                                const float* __restrict__ w,
                                                float* __restrict__ xmean,
                                                float* __restrict__ xmax)
{
    __shared__ float s[68][68];
    __shared__ float red[8];
    const int bc = blockIdx.x;          // b*512 + c
    const int c  = bc & 511, b = bc >> 9;
    float* plane = xz + (size_t)bc * kL;
    const int t = threadIdx.x;

    for (int idx = t; idx < 68 * 68; idx += 256) {
        int r = (idx / 68) - 2, col = (idx % 68) - 2;
        float v = 0.0f;
        if ((unsigned)r < 64u && (unsigned)col < 64u) v = plane[r * 64 + col];
        s[idx / 68][idx % 68] = v;
    }
    const float* wp = w + c * 25;
    float wr[25];
#pragma unroll
    for (int i = 0; i < 25; ++i) wr[i] = wp[i];
    __syncthreads();

    float lsum = 0.0f, lmax = -3.4e38f;
    float outv[16];
#pragma unroll
    for (int k = 0; k < 16; ++k) {
        int p = t + k * 256;
        int r = p >> 6, col = p & 63;
        float acc = 0.0f;
#pragma unroll
        for (int dr = 0; dr < 5; ++dr)
#pragma unroll
            for (int dc = 0; dc < 5; ++dc)
                acc = fmaf(s[r + dr][col + dc], wr[dr * 5 + dc], acc);
        outv[k] = acc;
        lsum += acc;
        lmax = fmaxf(lmax, acc);
    }
#pragma unroll
    for (int k = 0; k < 16; ++k) plane[t + k * 256] = outv[k];

    if (c < 256) {
        const int lane = t & 63, wv = t >> 6;
#pragma unroll
        for (int off = 32; off >= 1; off >>= 1) {
            lsum += __shfl_xor(lsum, off, 64);
            lmax = fmaxf(lmax, __shfl_xor(lmax, off, 64));
        }
        if (lane == 0) { red[wv] = lsum; red[4 + wv] = lmax; }
        __syncthreads();
        if (t == 0) {
            float ss = red[0] + red[1] + red[2] + red[3];
            float mm = fmaxf(fmaxf(red[4], red[5]), fmaxf(red[6], red[7]));
            xmean[b * 256 + c] = ss * (1.0f / 4096.0f);
            xmax[b * 256 + c]  = mm;
        }
    }
}

// ---------------------------------------------------------------------------
// Per-position mean/max over the 256 z channels.
// grid = 64 blocks: b = blk>>5, 128 l per block; 256 threads = 2 c-halves x 128 l.
// ---------------------------------------------------------------------------
__global__ __launch_bounds__(256) void k_zstats(const float* __restrict__ xz,
                                                float* __restrict__ smean,
                                                float* __restrict__ smax)
{
    __shared__ float ssum[256], smx[256];
    const int blk = blockIdx.x;
    const int b = blk >> 5, l0 = (blk & 31) * 128;
    const int t = threadIdx.x;
    const int l = l0 + (t & 127), half = t >> 7;
    const float* zb = xz + (size_t)(b * 512 + 256) * kL;
    float sum = 0.0f, mx = -3.4e38f;
    for (int c = half; c < 256; c += 2) {
        float v = zb[(size_t)c * kL + l];
        sum += v;
        mx = fmaxf(mx, v);
    }
    ssum[t] = sum; smx[t] = mx;
    __syncthreads();
    if (t < 128) {
        smean[b * kL + l] = (ssum[t] + ssum[t + 128]) * (1.0f / 256.0f);
        smax[b * kL + l]  = fmaxf(smx[t], smx[t + 128]);
    }
}

// Spatial-attention conv (k=7, pad 3) over L + sigmoid. grid = 2 (b).
__global__ __launch_bounds__(256) void k_att(const float* __restrict__ smean,
                                             const float* __restrict__ smax,
                                             const float* __restrict__ saw,
                                             float* __restrict__ att)
{
    const int b = blockIdx.x, t = threadIdx.x;
    float w0[7], w1[7];
#pragma unroll
    for (int i = 0; i < 7; ++i) { w0[i] = saw[i]; w1[i] = saw[7 + i]; }
    for (int l = t; l < kL; l += 256) {
        float acc = 0.0f;
#pragma unroll
        for (int k = 0; k < 7; ++k) {
            int ll = l + k - 3;
            if ((unsigned)ll < (unsigned)kL)
                acc += w0[k] * smean[b * kL + ll] + w1[k] * smax[b * kL + ll];
        }
        att[b * kL + l] = sigmoidf_(acc);
    }
}

// Channel-attention MLP -> per (b,c) gate. grid = 2 (b), 256 threads (t = c).
__global__ __launch_bounds__(256) void k_ca(const float* __restrict__ xmean,
                                            const float* __restrict__ xmax,
                                            const float* __restrict__ fc1,
                                            const float* __restrict__ fc2,
                                            float* __restrict__ gca)
{
    __shared__ float h[16];
    const int b = blockIdx.x, t = threadIdx.x;
    if (t < 16) {
        float ha = 0.0f, hm = 0.0f;
        for (int cc = 0; cc < 256; ++cc) {
            float w = fc1[t * 256 + cc];
            ha = fmaf(w, xmean[b * 256 + cc], ha);
            hm = fmaf(w, xmax[b * 256 + cc], hm);
        }
        h[t] = siluf_(ha) + siluf_(hm);
    }
    __syncthreads();
    float g = 0.0f;
#pragma unroll
    for (int r = 0; r < 16; ++r) g = fmaf(fc2[t * 16 + r], h[r], g);
    gca[b * 256 + t] = sigmoidf_(g);
}

// Causal depthwise conv1d (k=4) + CA gate (commutes with conv) + bias + SiLU.
// grid = 512 blocks (b*256 + c).
__global__ __launch_bounds__(256) void k_conv1d(const float* __restrict__ xz,
                                                const float* __restrict__ cw,
                                                const float* __restrict__ cb,
                                                const float* __restrict__ gca,
                                                float* __restrict__ xssm)
{
    __shared__ float row[kL + 3];
    const int bc = blockIdx.x;
    const int c = bc & 255, b = bc >> 8;
    const float* xp = xz + (size_t)(b * 512 + c) * kL;
    const int t = threadIdx.x;
    if (t < 3) row[t] = 0.0f;
    for (int l = t; l < kL; l += 256) row[3 + l] = xp[l];
    const float w0 = cw[c * 4], w1 = cw[c * 4 + 1], w2 = cw[c * 4 + 2], w3 = cw[c * 4 + 3];
    const float g = gca[b * 256 + c], bias = cb[c];
    __syncthreads();
    float* op = xssm + (size_t)bc * kL;
    for (int l = t; l < kL; l += 256) {
        float v = w0 * row[l] + w1 * row[l + 1] + w2 * row[l + 2] + w3 * row[l + 3];
        v = fmaf(g, v, bias);
        op[l] = siluf_(v);
    }
}

// x_proj: xdbl[b, l, e] = sum_d xw[e,d] * xssm[b,d,l]  (transposed output, 40/row)
// grid = 128 blocks (b * 64 l-tiles of 64), 512 threads = 8 waves x 64 lanes.
__global__ __launch_bounds__(512) void k_xproj(const float* __restrict__ xssm,
                                               const float* __restrict__ xw,
                                               float* __restrict__ xdbl)
{
    __shared__ float xs[256 * 64];
    const int blk = blockIdx.x;
    const int b = blk >> 6, l0 = (blk & 63) << 6;
    const int t = threadIdx.x;
    const float* xp = xssm + (size_t)(b * 256) * kL + l0;
    for (int idx = t; idx < 256 * 64; idx += 512) {
        int d = idx >> 6, l = idx & 63;
        xs[idx] = xp[(size_t)d * kL + l];
    }
    __syncthreads();
    const int wv = t >> 6, lane = t & 63;
    float acc[5] = {};
#pragma unroll 4
    for (int d = 0; d < 256; ++d) {
        float xv = xs[d * 64 + lane];
#pragma unroll
        for (int j = 0; j < 5; ++j)
            acc[j] = fmaf(xw[(wv * 5 + j) * 256 + d], xv, acc[j]);
    }
    float* op = xdbl + ((size_t)(b * kL + l0 + lane)) * 40 + wv * 5;
#pragma unroll
    for (int j = 0; j < 5; ++j) op[j] = acc[j];
}

// ---------------------------------------------------------------------------
// Selective scan, one block per (b,d). Fuses: delta = softplus(dtw . dt_lo + b),
// dA/dBu, parallel prefix scan over L (thread chunks of 16, wave shfl-scan,
// cross-wave compose), y = (scan + x*D) * silu(att*z). Writes y into xz x-half.
// ---------------------------------------------------------------------------
__global__ __launch_bounds__(256) void k_scan(const float* __restrict__ xdbl,
                                              const float* __restrict__ xssm,
                                              const float* __restrict__ xz,
                                              const float* __restrict__ att,
                                              const float* __restrict__ A_log,
                                              const float* __restrict__ Dv,
                                              const float* __restrict__ dtw,
                                              const float* __restrict__ dtb,
                                              float* __restrict__ y)
{
    __shared__ float delta_s[kL];
    __shared__ float x_s[kL];
    __shared__ float wt[2][4][16];
    __shared__ float pre[2][4][16];
    const int bd = blockIdx.x;
    const int d = bd & 255, b = bd >> 8;
    const int t = threadIdx.x;

    float An[16];
#pragma unroll
    for (int n = 0; n < 16; ++n) An[n] = -__expf(A_log[d * 16 + n]);
    float dw[8];
#pragma unroll
    for (int r = 0; r < 8; ++r) dw[r] = dtw[d * 8 + r];
    const float bias = dtb[d], Dd = Dv[d];
    const float* xrow = xssm + (size_t)bd * kL;

    for (int k = 0; k < 16; ++k) {
        int l = t + k * 256;
        const float* rp = xdbl + (size_t)(b * kL + l) * 40;
        float4 p0 = *(const float4*)rp;
        float4 p1 = *(const float4*)(rp + 4);
        float raw = bias + dw[0] * p0.x + dw[1] * p0.y + dw[2] * p0.z + dw[3] * p0.w
                         + dw[4] * p1.x + dw[5] * p1.y + dw[6] * p1.z + dw[7] * p1.w;
        delta_s[l] = softplusf_(raw);
        x_s[l] = xrow[l];
    }
    __syncthreads();

    // pass 1: per-thread local scan of its 16 timesteps
    float s[16], ap[16];
#pragma unroll
    for (int n = 0; n < 16; ++n) { s[n] = 0.0f; ap[n] = 1.0f; }
    const int base = t * 16;
    for (int j = 0; j < 16; ++j) {
        int l = base + j;
        float dl = delta_s[l], xl = x_s[l];
        const float* bp = xdbl + (size_t)(b * kL + l) * 40 + 8;
        float dx = dl * xl;
#pragma unroll
        for (int q = 0; q < 4; ++q) {
            float4 B4 = *(const float4*)(bp + q * 4);
            float a;
            a = __expf(dl * An[q * 4 + 0]); s[q * 4 + 0] = fmaf(s[q * 4 + 0], a, dx * B4.x); ap[q * 4 + 0] *= a;
            a = __expf(dl * An[q * 4 + 1]); s[q * 4 + 1] = fmaf(s[q * 4 + 1], a, dx * B4.y); ap[q * 4 + 1] *= a;
            a = __expf(dl * An[q * 4 + 2]); s[q * 4 + 2] = fmaf(s[q * 4 + 2], a, dx * B4.z); ap[q * 4 + 2] *= a;
            a = __expf(dl * An[q * 4 + 3]); s[q * 4 + 3] = fmaf(s[q * 4 + 3], a, dx * B4.w); ap[q * 4 + 3] *= a;
        }
    }

    // wave-level inclusive scan over chunks (compose (a, s) pairs)
    const int lane = t & 63, wv = t >> 6;
#pragma unroll
    for (int off = 1; off <= 32; off <<= 1) {
#pragma unroll
        for (int n = 0; n < 16; ++n) {
            float pa = __shfl_up(ap[n], (unsigned)off, 64);
            float ps = __shfl_up(s[n], (unsigned)off, 64);
            if (lane >= off) { s[n] = fmaf(ap[n], ps, s[n]); ap[n] *= pa; }
        }
    }
    // exclusive within wave
    float ea[16], es[16];
#pragma unroll
    for (int n = 0; n < 16; ++n) {
        ea[n] = __shfl_up(ap[n], 1u, 64);
        es[n] = __shfl_up(s[n], 1u, 64);
        if (lane == 0) { ea[n] = 1.0f; es[n] = 0.0f; }
    }
    if (lane == 63) {
#pragma unroll
        for (int n = 0; n < 16; ++n) { wt[0][wv][n] = ap[n]; wt[1][wv][n] = s[n]; }
    }
    __syncthreads();
    if (t < 16) {
        float pa = 1.0f, ps = 0.0f;
#pragma unroll
        for (int w2 = 0; w2 < 4; ++w2) {
            pre[0][w2][t] = pa; pre[1][w2][t] = ps;
            float ta = wt[0][w2][t], ts = wt[1][w2][t];
            ps = fmaf(ps, ta, ts);
            pa *= ta;
        }
    }
    __syncthreads();

    float st[16];
#pragma unroll
    for (int n = 0; n < 16; ++n) st[n] = fmaf(pre[1][wv][n], ea[n], es[n]);

    // pass 2: replay with true entry state, produce gated output
    const float* zrow = xz + (size_t)(b * 512 + 256 + d) * kL;
    const float* attb = att + b * kL;
    float* yrow = y + (size_t)(b * 512 + d) * kL;   // x-half rows of xz buffer
    for (int j = 0; j < 16; ++j) {
        int l = base + j;
        float dl = delta_s[l], xl = x_s[l];
        const float* bp = xdbl + (size_t)(b * kL + l) * 40 + 8;
        float dx = dl * xl;
        float yv = 0.0f;
#pragma unroll
        for (int q = 0; q < 4; ++q) {
            float4 B4 = *(const float4*)(bp + q * 4);
            float4 C4 = *(const float4*)(bp + 16 + q * 4);
            float a;
            a = __expf(dl * An[q * 4 + 0]); st[q * 4 + 0] = fmaf(st[q * 4 + 0], a, dx * B4.x); yv = fmaf(st[q * 4 + 0], C4.x, yv);
            a = __expf(dl * An[q * 4 + 1]); st[q * 4 + 1] = fmaf(st[q * 4 + 1], a, dx * B4.y); yv = fmaf(st[q * 4 + 1], C4.y, yv);
            a = __expf(dl * An[q * 4 + 2]); st[q * 4 + 2] = fmaf(st[q * 4 + 2], a, dx * B4.z); yv = fmaf(st[q * 4 + 2], C4.z, yv);
            a = __expf(dl * An[q * 4 + 3]); st[q * 4 + 3] = fmaf(st[q * 4 + 3], a, dx * B4.w); yv = fmaf(st[q * 4 + 3], C4.w, yv);
        }
        float zg = attb[l] * zrow[l];
        float outv = fmaf(xl, Dd, yv) * siluf_(zg);
        yrow[l] = outv;
    }
}

// ---------------------------------------------------------------------------
extern "C" void kernel_launch(void* const* d_in, const int* in_sizes, int n_in,
                              void* d_out, int out_size, void* d_ws, size_t ws_size,
                              hipStream_t stream)
{
    (void)in_sizes; (void)n_in; (void)out_size; (void)ws_size;
    const float* hidden    = (const float*)d_in[0];
    const float* in_proj_w = (const float*)d_in[1];
    const float* dwconv_w  = (const float*)d_in[2];
    const float* conv1d_w  = (const float*)d_in[3];
    const float* conv1d_b  = (const float*)d_in[4];
    const float* x_proj_w  = (const float*)d_in[5];
    const float* dt_proj_w = (const float*)d_in[6];
    const float* dt_proj_b = (const float*)d_in[7];
    const float* A_log     = (const float*)d_in[8];
    const float* Dvec      = (const float*)d_in[9];
    const float* out_proj_w= (const float*)d_in[10];
    const float* ca_fc1    = (const float*)d_in[11];
    const float* ca_fc2    = (const float*)d_in[12];
    const float* sa_w      = (const float*)d_in[13];
    float* out = (float*)d_out;
    float* ws  = (float*)d_ws;

    float* xz    = ws;                  // 2*512*4096           = 4,194,304 f
    float* xssm  = xz + 4194304;        // 2*256*4096           = 2,097,152 f
    float* xdbl  = xssm + 2097152;      // 2*4096*40            =   327,680 f
    float* xmean = xdbl + 327680;       // 512
    float* xmax  = xmean + 512;         // 512
    float* smean = xmax + 512;          // 8192
    float* smax  = smean + 8192;        // 8192
    float* att   = smax + 8192;         // 8192
    float* gca   = att + 8192;          // 512

    // 1. in_proj: xz = in_proj_w (512x128) @ hidden (2,128,4096)
    k_gemm<<<dim3(128, 8), 256, 0, stream>>>(in_proj_w, hidden, xz, 128, 128, 512);
    // 2. depthwise 5x5 conv (in place) + x-channel mean/max
    k_dwconv<<<1024, 256, 0, stream>>>(xz, dwconv_w, xmean, xmax);
    // 3. z per-position stats
    k_zstats<<<64, 256, 0, stream>>>(xz, smean, smax);
    // 4. spatial attention conv + sigmoid
    k_att<<<2, 256, 0, stream>>>(smean, smax, sa_w, att);
    // 5. channel attention gate
    k_ca<<<2, 256, 0, stream>>>(xmean, xmax, ca_fc1, ca_fc2, gca);
    // 6. gate + causal conv1d + bias + silu
    k_conv1d<<<512, 256, 0, stream>>>(xz, conv1d_w, conv1d_b, gca, xssm);
    // 7. x_proj -> transposed (b, l, 40)
    k_xproj<<<128, 512, 0, stream>>>(xssm, x_proj_w, xdbl);
    // 8. selective scan + gating; y written into xz x-half rows
    k_scan<<<512, 256, 0, stream>>>(xdbl, xssm, xz, att, A_log, Dvec,
                                    dt_proj_w, dt_proj_b, xz);
    // 9. out_proj: out = out_proj_w (128x256) @ y (rows b*512+d of xz)
    k_gemm<<<dim3(128, 2), 256, 0, stream>>>(out_proj_w, xz, out, 256, 512, 128);
}